// Round 1
// 123.159 us; speedup vs baseline: 1.1340x; 1.1340x over previous
//
#include <hip/hip_runtime.h>

// B=2, C=3, H=W=1024, fp32. R11 (LDS 16x16 tile + 6px halo) = 139.6us bench,
// ~70.5us/dispatch: VALUBusy 72%, HBM 19%, bank-conflict 2.0e7cy (~47%/CU)
// => co-bound VALU issue + LDS gather.
// R12: interior/border specialization. Drift bound: |pos - center| <= 4.5px
// (|v0|<=1, 3 advances |tf|<=1) => clamps/inb only matter in the outer block
// ring (252/4096 blocks). Interior path (94% of blocks):
//   - no coordinate clamps, no inb mask (provably no-ops -> bit-exact)
//   - corner offsets base+{0,1,29,30} const deltas => ds_read2_b32 merges
//   - PIXEL-space positions (x1024 exact pow2 scale => RN-invariant, exact)
//   - omx/omy hoisted once per corner (same ops, shared by 5 planes)
//   - skip color accum when ks[it]==0 (sigma=6 => ks[3]=0; a+=s*0 is exact
//     no-op; branch is block-uniform) => 144->120 LDS words/thread
// All changes arithmetic-identical => absmax must remain exactly 0.00390625.
constexpr int Bb = 2, Cc = 3, Hh = 1024, Ww = 1024;
constexpr int HWp = Hh * Ww;
constexpr int N_STEPS = 4;
constexpr int TS = 16;                  // pixels per tile side
constexpr int HALO = 6;                 // >= max drift 4.5 + margin
constexpr int TD = TS + 2 * HALO;       // 28
constexpr int TSTR = TD + 1;            // 29

struct Corn { int o00, o01, o10, o11; float wx, wy, omx, omy; };

// Interior: positions are pixel-space; never clamps. fx = px_pix - 0.5 is
// bit-identical to px_norm*1024 - 0.5 (the *1024 is exact).
__device__ __forceinline__ Corn mkcorn_int(float px, float py, int ox, int oy) {
#pragma clang fp contract(off)
    float fx = px - 0.5f;
    float fy = py - 0.5f;
    float fx0 = floorf(fx), fy0 = floorf(fy);
    Corn c;
    c.wx = fx - fx0;  c.wy = fy - fy0;
    c.omx = 1.0f - c.wx;  c.omy = 1.0f - c.wy;
    // local coords in [2,26] by the drift bound -- no clamps needed
    int o = ((int)fy0 - oy) * TSTR + ((int)fx0 - ox);
    c.o00 = o;        c.o01 = o + 1;
    c.o10 = o + TSTR; c.o11 = o + TSTR + 1;
    return c;
}

// Border: full clamp logic, identical arithmetic to R11 (pixel-space form).
__device__ __forceinline__ Corn mkcorn_bor(float px, float py, int ox, int oy) {
#pragma clang fp contract(off)
    float fx = px - 0.5f;
    float fy = py - 0.5f;
    float fx0 = floorf(fx), fy0 = floorf(fy);
    Corn c;
    c.wx = fx - fx0;  c.wy = fy - fy0;
    c.omx = 1.0f - c.wx;  c.omy = 1.0f - c.wy;
    int x0 = (int)fx0, y0 = (int)fy0;
    int x0i = min(max(x0, 0), Ww - 1);
    int x1i = min(x0i + 1, Ww - 1);
    int y0i = min(max(y0, 0), Hh - 1);
    int y1i = min(y0i + 1, Hh - 1);
    // local coords land in [0,27] even at image edges (clamps pull inward,
    // drift bound gives >=1 cell margin) -- defensive re-clamp removed.
    int lx0 = x0i - ox, lx1 = x1i - ox;
    int ly0 = y0i - oy, ly1 = y1i - oy;
    c.o00 = ly0 * TSTR + lx0;  c.o01 = ly0 * TSTR + lx1;
    c.o10 = ly1 * TSTR + lx0;  c.o11 = ly1 * TSTR + lx1;
    return c;
}

__device__ __forceinline__ float bsamp(const float* p, const Corn& c) {
#pragma clang fp contract(off)
    float v00 = p[c.o00], v01 = p[c.o01], v10 = p[c.o10], v11 = p[c.o11];
    float top = v00 * c.omx + v01 * c.wx;
    float bot = v10 * c.omx + v11 * c.wx;
    return top * c.omy + bot * c.wy;
}

template <bool BORDER>
__device__ __forceinline__ void run_tile(
    const float* __restrict__ x, const float* __restrict__ tg,
    const float* __restrict__ sg, float* __restrict__ out,
    float (&lds)[5][TD * TSTR])
{
#pragma clang fp contract(off)
    const int tx0 = blockIdx.x * TS, ty0 = blockIdx.y * TS;
    const int b = blockIdx.z;
    const int tid = threadIdx.x;          // 0..255

    const float* xp  = x  + (size_t)b * Cc * HWp;
    const float* txp = tg + (size_t)b * 2 * HWp;
    const float* planes[5] = { xp, xp + HWp, xp + 2 * HWp, txp, txp + HWp };
    const int ox = tx0 - HALO, oy = ty0 - HALO;

    // ---- uniform per-block kernel weights (hoisted above staging so the
    // expf/div chain overlaps the staging loads' latency)
    float sig = sg[b];
    float half_width = 2.0f * sig;
    float two_sigma2 = (2.0f * sig) * sig;
    const float stepf = (float)(1.0 / 0.3333);
    float ks[N_STEPS];
#pragma unroll
    for (int it = 0; it < N_STEPS; ++it) {
        float r = ((float)it + 1.0f) * stepf;
        float k = expf(-(r * r) / two_sigma2);
        ks[it] = (r < half_width) ? k : 0.0f;
    }

    // ---- stage 28x28 x 5 planes into LDS (clamped only on border blocks)
    for (int e = tid; e < TD * TD; e += 256) {
        int r = e / TD, cc = e - r * TD;
        int gy = oy + r, gx = ox + cc;
        if (BORDER) {
            gy = min(max(gy, 0), Hh - 1);
            gx = min(max(gx, 0), Ww - 1);
        }
        int g = gy * Ww + gx;
#pragma unroll
        for (int pl = 0; pl < 5; ++pl)
            lds[pl][r * TSTR + cc] = planes[pl][g];
    }
    __syncthreads();

    // ---- per-pixel march (all gathers from LDS), positions in PIXEL units
    const int lx = tid & (TS - 1), ly = tid >> 4;
    const int j = tx0 + lx, i = ty0 + ly;
    const int ctr = (HALO + ly) * TSTR + (HALO + lx);

    const float psx = (float)j + 0.5f;    // == ((j+0.5)/1024)*1024 exact
    const float psy = (float)i + 0.5f;

    float v0x = lds[3][ctr];
    float v0y = lds[4][ctr];

    float c1a = 0.f, c1b = 0.f, c1c = 0.f, s1 = 0.f;
    float c2a = 0.f, c2b = 0.f, c2c = 0.f, s2 = 0.f;

#pragma unroll
    for (int d = 0; d < 2; ++d) {
        float vx = d ? -v0x : v0x;
        float vy = d ? -v0y : v0y;
        float px = psx + vx;              // p0 = p_start + v0/tex  (x1024)
        float py = psy + vy;
        float a0 = 0.f, a1 = 0.f, a2 = 0.f, as = 0.f;
#pragma unroll
        for (int it = 0; it < N_STEPS; ++it) {
            Corn c = BORDER ? mkcorn_bor(px, py, ox, oy)
                            : mkcorn_int(px, py, ox, oy);
            if (ks[it] != 0.0f) {         // block-uniform; skip is bit-exact
                float w = ks[it];
                if (BORDER) {
                    bool inb = (px >= 0.0f) && (px < 1024.0f) &&
                               (py >= 0.0f) && (py < 1024.0f);
                    w = inb ? w : 0.0f;
                }
                a0 += bsamp(lds[0], c) * w;
                a1 += bsamp(lds[1], c) * w;
                a2 += bsamp(lds[2], c) * w;
                as += w;
            }
            if (it == N_STEPS - 1) break; // ref discards final advance
            float tfx = bsamp(lds[3], c);
            float tfy = bsamp(lds[4], c);
            float vt = (vx * tfx) + (vy * tfy);
            if (vt < 0.0f) { tfx = -tfx; tfy = -tfy; }
            px = px + tfx;                // p += tf/tex, scaled x1024 (exact)
            py = py + tfy;
            vx = tfx; vy = tfy;
        }
        if (d == 0) { c1a = a0; c1b = a1; c1c = a2; s1 = as; }
        else        { c2a = a0; c2b = a1; c2c = a2; s2 = as; }
    }

    const int pix = i * Ww + j;
    float xc0 = lds[0][ctr], xc1 = lds[1][ctr], xc2 = lds[2][ctr];
    float denom = (1.0f + s1) + s2;
    float* op = out + (size_t)b * Cc * HWp;
    op[pix]           = ((xc0 + c1a) + c2a) / denom;   // keep exact divides
    op[pix + HWp]     = ((xc1 + c1b) + c2b) / denom;
    op[pix + 2 * HWp] = ((xc2 + c1c) + c2c) / denom;
}

__global__ __launch_bounds__(256) void flow_smooth_kernel(
    const float* __restrict__ x,
    const float* __restrict__ tg,
    const float* __restrict__ sg,
    float* __restrict__ out)
{
    __shared__ float lds[5][TD * TSTR];   // 16.2 KB
    // Clamps/inb can only trigger when the tile's +/-6px halo region or
    // +/-5px sample range touches the image edge: outer ring of blocks only.
    const bool border = (blockIdx.x == 0) || (blockIdx.x == gridDim.x - 1) ||
                        (blockIdx.y == 0) || (blockIdx.y == gridDim.y - 1);
    if (border) run_tile<true >(x, tg, sg, out, lds);
    else        run_tile<false>(x, tg, sg, out, lds);
}

extern "C" void kernel_launch(void* const* d_in, const int* in_sizes, int n_in,
                              void* d_out, int out_size, void* d_ws, size_t ws_size,
                              hipStream_t stream) {
    const float* x = nullptr; const float* tg = nullptr; const float* sg = nullptr;
    for (int t = 0; t < n_in; ++t) {
        if (in_sizes[t] == Bb * Cc * HWp)      x  = (const float*)d_in[t];
        else if (in_sizes[t] == Bb * 2 * HWp)  tg = (const float*)d_in[t];
        else                                   sg = (const float*)d_in[t];
    }
    float* out = (float*)d_out;

    dim3 block(256, 1, 1);
    dim3 grid(Ww / TS, Hh / TS, Bb);   // 64 x 64 x 2 = 8192 blocks
    flow_smooth_kernel<<<grid, block, 0, stream>>>(x, tg, sg, out);
}